// Round 1
// baseline (379.511 us; speedup 1.0000x reference)
//
#include <hip/hip_runtime.h>
#include <hip/hip_bf16.h>

#define D_MODEL 384
#define N_HEAD  6
#define HEAD    64
#define T_LEN   256
#define BATCH   128
#define MROWS   (BATCH * T_LEN)   // 32768
#define FF      1536

typedef __bf16 bf16x8 __attribute__((ext_vector_type(8)));
typedef float  f32x4  __attribute__((ext_vector_type(4)));
typedef unsigned short us8 __attribute__((ext_vector_type(8)));
using bf16 = __hip_bfloat16;

__device__ inline f32x4 mfma16(bf16x8 a, bf16x8 b, f32x4 c) {
    return __builtin_amdgcn_mfma_f32_16x16x32_bf16(a, b, c, 0, 0, 0);
}

// ---------------- weight prep: cast to bf16, transpose to [N][K] ----------------
__global__ __launch_bounds__(256) void prep_w(
    const float* __restrict__ Wq, const float* __restrict__ Wk, const float* __restrict__ Wv,
    const float* __restrict__ Wp, const float* __restrict__ W1, const float* __restrict__ W2,
    bf16* __restrict__ Wqkv_t, bf16* __restrict__ Wp_t,
    bf16* __restrict__ W1_t,   bf16* __restrict__ W2_t)
{
    int i = blockIdx.x * 256 + threadIdx.x;
    if (i < 1152 * 384) {
        int cc = i / 384, d = i - cc * 384;
        const float* src = cc < 384 ? Wq : (cc < 768 ? Wk : Wv);
        int c = cc < 384 ? cc : (cc < 768 ? cc - 384 : cc - 768);
        int h = c >> 6, e = c & 63;
        Wqkv_t[i] = __float2bfloat16(src[(h * 384 + d) * 64 + e]);
    }
    if (i < 384 * 384) {
        int o = i / 384, d = i - o * 384;
        Wp_t[i] = __float2bfloat16(Wp[d * 384 + o]);
    }
    if (i < 1536 * 384) {
        int o = i / 384, d = i - o * 384;          // W1_t[o][d], o in [0,1536)
        W1_t[i] = __float2bfloat16(W1[d * 1536 + o]);
        int o2 = i / 1536, d2 = i - o2 * 1536;     // W2_t[o2][d2], o2 in [0,384)
        W2_t[i] = __float2bfloat16(W2[d2 * 384 + o2]);
    }
}

// ---------------- layernorm: one wave per row of 384 ----------------
__global__ __launch_bounds__(256) void ln_k(
    const float* __restrict__ xin, const float* __restrict__ gg,
    const float* __restrict__ bb, bf16* __restrict__ outb)
{
    int wid  = blockIdx.x * 4 + (threadIdx.x >> 6);
    int lane = threadIdx.x & 63;
    const float* xr = xin + (size_t)wid * 384;
    float v[6]; float s = 0.f;
#pragma unroll
    for (int i = 0; i < 6; ++i) { v[i] = xr[lane + i * 64]; s += v[i]; }
#pragma unroll
    for (int mk = 1; mk < 64; mk <<= 1) s += __shfl_xor(s, mk);
    float mu = s * (1.f / 384.f);
    float vs = 0.f;
#pragma unroll
    for (int i = 0; i < 6; ++i) { float d = v[i] - mu; vs += d * d; }
#pragma unroll
    for (int mk = 1; mk < 64; mk <<= 1) vs += __shfl_xor(vs, mk);
    float rs = rsqrtf(vs * (1.f / 384.f) + 1e-5f);
    bf16* orow = outb + (size_t)wid * 384;
#pragma unroll
    for (int i = 0; i < 6; ++i) {
        int c = lane + i * 64;
        orow[c] = __float2bfloat16((v[i] - mu) * rs * gg[c] + bb[c]);
    }
}

// ---------------- generic MFMA GEMM: C[M,N] = A[M,K] @ Bt[N,K]^T (+epilogue) ----
enum { EPI_QKV = 0, EPI_PROJ = 1, EPI_FFN1 = 2, EPI_FFN2 = 3 };

template<int EPI>
__global__ __launch_bounds__(256) void gemm_k(
    const bf16* __restrict__ A, const bf16* __restrict__ Bt, int K,
    const float* __restrict__ bias, const float* __restrict__ resid,
    float* __restrict__ outf,
    bf16* __restrict__ outq, bf16* __restrict__ outk, bf16* __restrict__ outv,
    bf16* __restrict__ outb)
{
    __shared__ bf16 Asm[128][64];
    __shared__ bf16 Bsm[128][64];
    int bid = blockIdx.x;
    int mt = bid % (MROWS / 128);
    int nt = bid / (MROWS / 128);
    int m0 = mt * 128, n0 = nt * 128;
    int tid = threadIdx.x, lane = tid & 63, w = tid >> 6;
    int wm = (w >> 1) * 64, wn = (w & 1) * 64;
    int r = lane & 15, g = lane >> 4, ko = g << 3;

    f32x4 acc[4][4];
#pragma unroll
    for (int i = 0; i < 4; ++i)
#pragma unroll
        for (int j = 0; j < 4; ++j) acc[i][j] = (f32x4){0.f, 0.f, 0.f, 0.f};

    for (int k0 = 0; k0 < K; k0 += 64) {
#pragma unroll
        for (int j = 0; j < 4; ++j) {
            int c = tid + j * 256;            // 1024 chunks of 16B per matrix
            int row = c >> 3, kc = (c & 7) << 3;
            *(us8*)&Asm[row][kc] = *(const us8*)&A[(size_t)(m0 + row) * K + k0 + kc];
            *(us8*)&Bsm[row][kc] = *(const us8*)&Bt[(size_t)(n0 + row) * K + k0 + kc];
        }
        __syncthreads();
#pragma unroll
        for (int kk = 0; kk < 2; ++kk) {
            bf16x8 af[4], bfr[4];
#pragma unroll
            for (int i = 0; i < 4; ++i) af[i]  = *(const bf16x8*)&Asm[wm + i * 16 + r][ko + kk * 32];
#pragma unroll
            for (int i = 0; i < 4; ++i) bfr[i] = *(const bf16x8*)&Bsm[wn + i * 16 + r][ko + kk * 32];
#pragma unroll
            for (int mi = 0; mi < 4; ++mi)
#pragma unroll
                for (int ni = 0; ni < 4; ++ni)
                    acc[mi][ni] = mfma16(af[mi], bfr[ni], acc[mi][ni]);
        }
        __syncthreads();
    }

#pragma unroll
    for (int ni = 0; ni < 4; ++ni) {
        int n = n0 + wn + ni * 16 + r;
        float bn = 0.f;
        if constexpr (EPI == EPI_PROJ || EPI == EPI_FFN1 || EPI == EPI_FFN2) bn = bias[n];
#pragma unroll
        for (int mi = 0; mi < 4; ++mi) {
#pragma unroll
            for (int j = 0; j < 4; ++j) {
                int m = m0 + wm + mi * 16 + (g << 2) + j;
                float v = acc[mi][ni][j];
                if constexpr (EPI == EPI_QKV) {
                    int b = m >> 8, t = m & 255;
                    if (n < 384) {
                        int h = n >> 6, e = n & 63;
                        outq[((size_t)(b * N_HEAD + h) * T_LEN + t) * HEAD + e] = __float2bfloat16(v);
                    } else if (n < 768) {
                        int c = n - 384; int h = c >> 6, e = c & 63;
                        outk[((size_t)(b * N_HEAD + h) * T_LEN + t) * HEAD + e] = __float2bfloat16(v);
                    } else {
                        int c = n - 768; int h = c >> 6, e = c & 63;
                        outv[((size_t)(b * N_HEAD + h) * HEAD + e) * T_LEN + t] = __float2bfloat16(v);
                    }
                } else if constexpr (EPI == EPI_PROJ || EPI == EPI_FFN2) {
                    outf[(size_t)m * 384 + n] = resid[(size_t)m * 384 + n] + v + bn;
                } else { // FFN1
                    float z = v + bn; z = z > 0.f ? z : 0.f;
                    outb[(size_t)m * FF + n] = __float2bfloat16(z);
                }
            }
        }
    }
}

// ---------------- causal flash attention: block = (b,h,64-row q tile) ----------
__global__ __launch_bounds__(256) void attn_k(
    const bf16* __restrict__ q, const bf16* __restrict__ k,
    const bf16* __restrict__ vT, bf16* __restrict__ att)
{
    __shared__ bf16 Ksm[64][64];
    __shared__ bf16 Vsm[64][64];   // Vsm[e][s_local]
    __shared__ bf16 Psm[4][16][64];
    int bid = blockIdx.x;
    int qt = bid & 3, bh = bid >> 2;
    int q0 = qt * 64;
    int tid = threadIdx.x, lane = tid & 63, w = tid >> 6;
    int r = lane & 15, g = lane >> 4, ko = g << 3;

    const bf16* qp = q + ((size_t)bh * T_LEN + q0 + w * 16) * HEAD;
    bf16x8 qf[2];
    qf[0] = *(const bf16x8*)&qp[r * HEAD + ko];
    qf[1] = *(const bf16x8*)&qp[r * HEAD + ko + 32];

    f32x4 o[4];
#pragma unroll
    for (int i = 0; i < 4; ++i) o[i] = (f32x4){0.f, 0.f, 0.f, 0.f};
    float mrow[4], lrow[4];
#pragma unroll
    for (int j = 0; j < 4; ++j) { mrow[j] = -3.0e38f; lrow[j] = 0.f; }

    for (int st = 0; st <= qt; ++st) {
        int s0 = st * 64;
#pragma unroll
        for (int j2 = 0; j2 < 2; ++j2) {
            int c = tid + j2 * 256;           // 512 chunks of 16B per matrix
            int row = c >> 3, kc = (c & 7) << 3;
            *(us8*)&Ksm[row][kc] = *(const us8*)&k [((size_t)bh * T_LEN + s0 + row) * HEAD + kc];
            *(us8*)&Vsm[row][kc] = *(const us8*)&vT[((size_t)bh * HEAD + row) * T_LEN + s0 + kc];
        }
        __syncthreads();

        f32x4 s[4];
#pragma unroll
        for (int i = 0; i < 4; ++i) s[i] = (f32x4){0.f, 0.f, 0.f, 0.f};
#pragma unroll
        for (int kk = 0; kk < 2; ++kk) {
#pragma unroll
            for (int ni = 0; ni < 4; ++ni) {
                bf16x8 kf = *(const bf16x8*)&Ksm[ni * 16 + r][kk * 32 + ko];
                s[ni] = mfma16(qf[kk], kf, s[ni]);
            }
        }
        // scale + causal mask + per-row (16-lane-group) online softmax
        int qrow = q0 + w * 16 + (g << 2);
        float tmax[4], fsc[4], tsum[4];
#pragma unroll
        for (int j = 0; j < 4; ++j) {
            float mx = -3.0e38f;
#pragma unroll
            for (int ni = 0; ni < 4; ++ni) {
                int col = s0 + ni * 16 + r;
                float sv = (col <= qrow + j) ? s[ni][j] * 0.125f : -3.0e38f;
                s[ni][j] = sv;
                mx = fmaxf(mx, sv);
            }
            tmax[j] = mx;
        }
#pragma unroll
        for (int mk = 1; mk < 16; mk <<= 1)
#pragma unroll
            for (int j = 0; j < 4; ++j) tmax[j] = fmaxf(tmax[j], __shfl_xor(tmax[j], mk));
#pragma unroll
        for (int j = 0; j < 4; ++j) {
            float mnew = fmaxf(mrow[j], tmax[j]);
            fsc[j] = __expf(mrow[j] - mnew);
            mrow[j] = mnew;
            float ss = 0.f;
#pragma unroll
            for (int ni = 0; ni < 4; ++ni) {
                float p = __expf(s[ni][j] - mnew);
                s[ni][j] = p; ss += p;
            }
            tsum[j] = ss;
        }
#pragma unroll
        for (int mk = 1; mk < 16; mk <<= 1)
#pragma unroll
            for (int j = 0; j < 4; ++j) tsum[j] += __shfl_xor(tsum[j], mk);
#pragma unroll
        for (int j = 0; j < 4; ++j) lrow[j] = lrow[j] * fsc[j] + tsum[j];
#pragma unroll
        for (int ni = 0; ni < 4; ++ni)
#pragma unroll
            for (int j = 0; j < 4; ++j) o[ni][j] *= fsc[j];
        // P -> LDS (bf16), per-wave buffer, then PV
#pragma unroll
        for (int ni = 0; ni < 4; ++ni)
#pragma unroll
            for (int j = 0; j < 4; ++j)
                Psm[w][(g << 2) + j][ni * 16 + r] = __float2bfloat16(s[ni][j]);
#pragma unroll
        for (int kk = 0; kk < 2; ++kk) {
            bf16x8 pf = *(const bf16x8*)&Psm[w][r][kk * 32 + ko];
#pragma unroll
            for (int ni = 0; ni < 4; ++ni) {
                bf16x8 vf = *(const bf16x8*)&Vsm[ni * 16 + r][kk * 32 + ko];
                o[ni] = mfma16(pf, vf, o[ni]);
            }
        }
        __syncthreads();
    }

    int b = bh / N_HEAD, h = bh % N_HEAD;
#pragma unroll
    for (int ni = 0; ni < 4; ++ni)
#pragma unroll
        for (int j = 0; j < 4; ++j) {
            int t = q0 + w * 16 + (g << 2) + j;
            int e = h * HEAD + ni * 16 + r;
            att[((size_t)b * T_LEN + t) * D_MODEL + e] = __float2bfloat16(o[ni][j] / lrow[j]);
        }
}

// ---------------- launch ----------------
extern "C" void kernel_launch(void* const* d_in, const int* in_sizes, int n_in,
                              void* d_out, int out_size, void* d_ws, size_t ws_size,
                              hipStream_t stream)
{
    const float* x   = (const float*)d_in[0];
    const float* Wq  = (const float*)d_in[1];
    const float* Wk  = (const float*)d_in[2];
    const float* Wv  = (const float*)d_in[3];
    const float* Wp  = (const float*)d_in[4];
    const float* bp  = (const float*)d_in[5];
    const float* W1  = (const float*)d_in[6];
    const float* b1  = (const float*)d_in[7];
    const float* W2  = (const float*)d_in[8];
    const float* b2  = (const float*)d_in[9];
    const float* g1  = (const float*)d_in[10];
    const float* be1 = (const float*)d_in[11];
    const float* g2  = (const float*)d_in[12];
    const float* be2 = (const float*)d_in[13];
    float* out = (float*)d_out;

    char* ws = (char*)d_ws;
    size_t off = 0;
    auto alloc = [&](size_t bytes) { void* p = ws + off; off += (bytes + 255) & ~(size_t)255; return p; };
    bf16* Wqkv_t = (bf16*)alloc((size_t)1152 * 384 * 2);
    bf16* Wp_t   = (bf16*)alloc((size_t)384 * 384 * 2);
    bf16* W1_t   = (bf16*)alloc((size_t)1536 * 384 * 2);
    bf16* W2_t   = (bf16*)alloc((size_t)384 * 1536 * 2);
    bf16* h      = (bf16*)alloc((size_t)MROWS * 384 * 2);   // also h2 later
    bf16* qb     = (bf16*)alloc((size_t)MROWS * 384 * 2);
    bf16* kb     = (bf16*)alloc((size_t)MROWS * 384 * 2);
    bf16* vTb    = (bf16*)alloc((size_t)MROWS * 384 * 2);
    bf16* attb   = (bf16*)alloc((size_t)MROWS * 384 * 2);
    float* x1    = (float*)alloc((size_t)MROWS * 384 * 4);
    bf16* ff1    = qb;  // alias: q/k/vT/att dead by FFN1 time (exactly 100663296 B)

    prep_w<<<2304, 256, 0, stream>>>(Wq, Wk, Wv, Wp, W1, W2, Wqkv_t, Wp_t, W1_t, W2_t);
    ln_k<<<MROWS / 4, 256, 0, stream>>>(x, g1, be1, h);
    gemm_k<EPI_QKV><<<(MROWS / 128) * 9, 256, 0, stream>>>(
        h, Wqkv_t, 384, nullptr, nullptr, nullptr, qb, kb, vTb, nullptr);
    attn_k<<<BATCH * N_HEAD * 4, 256, 0, stream>>>(qb, kb, vTb, attb);
    gemm_k<EPI_PROJ><<<(MROWS / 128) * 3, 256, 0, stream>>>(
        attb, Wp_t, 384, bp, x, x1, nullptr, nullptr, nullptr, nullptr);
    ln_k<<<MROWS / 4, 256, 0, stream>>>(x1, g2, be2, h);
    gemm_k<EPI_FFN1><<<(MROWS / 128) * 12, 256, 0, stream>>>(
        h, W1_t, 384, b1, nullptr, nullptr, nullptr, nullptr, nullptr, ff1);
    gemm_k<EPI_FFN2><<<(MROWS / 128) * 3, 256, 0, stream>>>(
        ff1, W2_t, 1536, b2, x1, out, nullptr, nullptr, nullptr, nullptr);
}

// Round 2
// 373.648 us; speedup vs baseline: 1.0157x; 1.0157x over previous
//
#include <hip/hip_runtime.h>
#include <hip/hip_bf16.h>

#define D_MODEL 384
#define N_HEAD  6
#define HEAD    64
#define T_LEN   256
#define BATCH   128
#define MROWS   (BATCH * T_LEN)   // 32768
#define FF      1536

typedef __bf16 bf16x8 __attribute__((ext_vector_type(8)));
typedef float  f32x4  __attribute__((ext_vector_type(4)));
typedef unsigned short us8 __attribute__((ext_vector_type(8)));
using bf16 = __hip_bfloat16;

__device__ inline f32x4 mfma16(bf16x8 a, bf16x8 b, f32x4 c) {
    return __builtin_amdgcn_mfma_f32_16x16x32_bf16(a, b, c, 0, 0, 0);
}

// async global->LDS, 16B per lane; LDS dest = wave-uniform base + lane*16
#define GLOAD_LDS16(g, l) __builtin_amdgcn_global_load_lds( \
    (const __attribute__((address_space(1))) unsigned int*)(g), \
    (__attribute__((address_space(3))) unsigned int*)(l), 16, 0, 0)

// ---------------- weight prep: cast to bf16, transpose to [N][K] ----------------
__global__ __launch_bounds__(256) void prep_w(
    const float* __restrict__ Wq, const float* __restrict__ Wk, const float* __restrict__ Wv,
    const float* __restrict__ Wp, const float* __restrict__ W1, const float* __restrict__ W2,
    bf16* __restrict__ Wqkv_t, bf16* __restrict__ Wp_t,
    bf16* __restrict__ W1_t,   bf16* __restrict__ W2_t)
{
    int i = blockIdx.x * 256 + threadIdx.x;
    if (i < 1152 * 384) {
        int cc = i / 384, d = i - cc * 384;
        const float* src = cc < 384 ? Wq : (cc < 768 ? Wk : Wv);
        int c = cc < 384 ? cc : (cc < 768 ? cc - 384 : cc - 768);
        int h = c >> 6, e = c & 63;
        Wqkv_t[i] = __float2bfloat16(src[(h * 384 + d) * 64 + e]);
    }
    if (i < 384 * 384) {
        int o = i / 384, d = i - o * 384;
        Wp_t[i] = __float2bfloat16(Wp[d * 384 + o]);
    }
    if (i < 1536 * 384) {
        int o = i / 384, d = i - o * 384;          // W1_t[o][d], o in [0,1536)
        W1_t[i] = __float2bfloat16(W1[d * 1536 + o]);
        int o2 = i / 1536, d2 = i - o2 * 1536;     // W2_t[o2][d2], o2 in [0,384)
        W2_t[i] = __float2bfloat16(W2[d2 * 384 + o2]);
    }
}

// ---------------- layernorm: one wave per row of 384 ----------------
__global__ __launch_bounds__(256) void ln_k(
    const float* __restrict__ xin, const float* __restrict__ gg,
    const float* __restrict__ bb, bf16* __restrict__ outb)
{
    int wid  = blockIdx.x * 4 + (threadIdx.x >> 6);
    int lane = threadIdx.x & 63;
    const float* xr = xin + (size_t)wid * 384;
    float v[6]; float s = 0.f;
#pragma unroll
    for (int i = 0; i < 6; ++i) { v[i] = xr[lane + i * 64]; s += v[i]; }
#pragma unroll
    for (int mk = 1; mk < 64; mk <<= 1) s += __shfl_xor(s, mk);
    float mu = s * (1.f / 384.f);
    float vs = 0.f;
#pragma unroll
    for (int i = 0; i < 6; ++i) { float d = v[i] - mu; vs += d * d; }
#pragma unroll
    for (int mk = 1; mk < 64; mk <<= 1) vs += __shfl_xor(vs, mk);
    float rs = rsqrtf(vs * (1.f / 384.f) + 1e-5f);
    bf16* orow = outb + (size_t)wid * 384;
#pragma unroll
    for (int i = 0; i < 6; ++i) {
        int c = lane + i * 64;
        orow[c] = __float2bfloat16((v[i] - mu) * rs * gg[c] + bb[c]);
    }
}

// ---------------- generic MFMA GEMM: C[M,N] = A[M,K] @ Bt[N,K]^T (+epilogue) ----
enum { EPI_QKV = 0, EPI_PROJ = 1, EPI_FFN1 = 2, EPI_FFN2 = 3 };

template<int EPI>
__global__ __launch_bounds__(256) void gemm_k(
    const bf16* __restrict__ A, const bf16* __restrict__ Bt, int K,
    const float* __restrict__ bias, const float* __restrict__ resid,
    float* __restrict__ outf,
    bf16* __restrict__ outq, bf16* __restrict__ outk, bf16* __restrict__ outv,
    bf16* __restrict__ outb)
{
    __shared__ bf16 Asm[128][64];
    __shared__ bf16 Bsm[128][64];
    int bid = blockIdx.x;
    int mt = bid % (MROWS / 128);
    int nt = bid / (MROWS / 128);
    int m0 = mt * 128, n0 = nt * 128;
    int tid = threadIdx.x, lane = tid & 63, w = tid >> 6;
    int wm = (w >> 1) * 64, wn = (w & 1) * 64;
    int r = lane & 15, g = lane >> 4, ko = g << 3;
    int lr = lane >> 3;          // row within 8-row segment
    int lc = (lane & 7) << 3;    // element offset within 64-elem row

    f32x4 acc[4][4];
#pragma unroll
    for (int i = 0; i < 4; ++i)
#pragma unroll
        for (int j = 0; j < 4; ++j) acc[i][j] = (f32x4){0.f, 0.f, 0.f, 0.f};

    for (int k0 = 0; k0 < K; k0 += 64) {
        // async staging: wave w fills rows [w*32, w*32+32) of Asm and Bsm
        const bf16* abase = A  + (size_t)(m0 + w * 32 + lr) * K + k0 + lc;
        const bf16* bbase = Bt + (size_t)(n0 + w * 32 + lr) * K + k0 + lc;
#pragma unroll
        for (int s = 0; s < 4; ++s) {
            GLOAD_LDS16(abase + (size_t)(s * 8) * K, &Asm[w * 32 + s * 8][0]);
            GLOAD_LDS16(bbase + (size_t)(s * 8) * K, &Bsm[w * 32 + s * 8][0]);
        }
        __syncthreads();
#pragma unroll
        for (int kk = 0; kk < 2; ++kk) {
            bf16x8 af[4], bfr[4];
#pragma unroll
            for (int i = 0; i < 4; ++i) af[i]  = *(const bf16x8*)&Asm[wm + i * 16 + r][ko + kk * 32];
#pragma unroll
            for (int i = 0; i < 4; ++i) bfr[i] = *(const bf16x8*)&Bsm[wn + i * 16 + r][ko + kk * 32];
#pragma unroll
            for (int mi = 0; mi < 4; ++mi)
#pragma unroll
                for (int ni = 0; ni < 4; ++ni)
                    acc[mi][ni] = mfma16(af[mi], bfr[ni], acc[mi][ni]);
        }
        __syncthreads();
    }

#pragma unroll
    for (int ni = 0; ni < 4; ++ni) {
        int n = n0 + wn + ni * 16 + r;
        float bn = 0.f;
        if constexpr (EPI == EPI_PROJ || EPI == EPI_FFN1 || EPI == EPI_FFN2) bn = bias[n];
#pragma unroll
        for (int mi = 0; mi < 4; ++mi) {
#pragma unroll
            for (int j = 0; j < 4; ++j) {
                int m = m0 + wm + mi * 16 + (g << 2) + j;
                float v = acc[mi][ni][j];
                if constexpr (EPI == EPI_QKV) {
                    int b = m >> 8, t = m & 255;
                    if (n < 384) {
                        int h = n >> 6, e = n & 63;
                        outq[((size_t)(b * N_HEAD + h) * T_LEN + t) * HEAD + e] = __float2bfloat16(v);
                    } else if (n < 768) {
                        int c = n - 384; int h = c >> 6, e = c & 63;
                        outk[((size_t)(b * N_HEAD + h) * T_LEN + t) * HEAD + e] = __float2bfloat16(v);
                    } else {
                        int c = n - 768; int h = c >> 6, e = c & 63;
                        outv[((size_t)(b * N_HEAD + h) * HEAD + e) * T_LEN + t] = __float2bfloat16(v);
                    }
                } else if constexpr (EPI == EPI_PROJ || EPI == EPI_FFN2) {
                    outf[(size_t)m * 384 + n] = resid[(size_t)m * 384 + n] + v + bn;
                } else { // FFN1
                    float z = v + bn; z = z > 0.f ? z : 0.f;
                    outb[(size_t)m * FF + n] = __float2bfloat16(z);
                }
            }
        }
    }
}

// ---------------- causal flash attention: block = (b,h,64-row q tile) ----------
__global__ __launch_bounds__(256) void attn_k(
    const bf16* __restrict__ q, const bf16* __restrict__ k,
    const bf16* __restrict__ vT, bf16* __restrict__ att)
{
    __shared__ bf16 Ksm[64][64];
    __shared__ bf16 Vsm[64][64];   // Vsm[e][s_local]
    __shared__ bf16 Psm[4][16][64];
    int bid = blockIdx.x;
    int qt = bid & 3, bh = bid >> 2;
    int q0 = qt * 64;
    int tid = threadIdx.x, lane = tid & 63, w = tid >> 6;
    int r = lane & 15, g = lane >> 4, ko = g << 3;
    int lr = lane >> 3, lc = (lane & 7) << 3;

    const bf16* qp = q + ((size_t)bh * T_LEN + q0 + w * 16) * HEAD;
    bf16x8 qf[2];
    qf[0] = *(const bf16x8*)&qp[r * HEAD + ko];
    qf[1] = *(const bf16x8*)&qp[r * HEAD + ko + 32];

    f32x4 o[4];
#pragma unroll
    for (int i = 0; i < 4; ++i) o[i] = (f32x4){0.f, 0.f, 0.f, 0.f};
    float mrow[4], lrow[4];
#pragma unroll
    for (int j = 0; j < 4; ++j) { mrow[j] = -3.0e38f; lrow[j] = 0.f; }

    for (int st = 0; st <= qt; ++st) {
        int s0 = st * 64;
        // async staging: wave w fills rows [w*16, w*16+16) of Ksm and Vsm
#pragma unroll
        for (int s = 0; s < 2; ++s) {
            int row0 = w * 16 + s * 8;
            GLOAD_LDS16(k  + ((size_t)bh * T_LEN + s0 + row0 + lr) * HEAD + lc, &Ksm[row0][0]);
            GLOAD_LDS16(vT + ((size_t)bh * HEAD + row0 + lr) * T_LEN + s0 + lc, &Vsm[row0][0]);
        }
        __syncthreads();

        f32x4 s[4];
#pragma unroll
        for (int i = 0; i < 4; ++i) s[i] = (f32x4){0.f, 0.f, 0.f, 0.f};
#pragma unroll
        for (int kk = 0; kk < 2; ++kk) {
#pragma unroll
            for (int ni = 0; ni < 4; ++ni) {
                bf16x8 kf = *(const bf16x8*)&Ksm[ni * 16 + r][kk * 32 + ko];
                s[ni] = mfma16(qf[kk], kf, s[ni]);
            }
        }
        // scale + causal mask + per-row (16-lane-group) online softmax
        int qrow = q0 + w * 16 + (g << 2);
        float tmax[4], fsc[4], tsum[4];
#pragma unroll
        for (int j = 0; j < 4; ++j) {
            float mx = -3.0e38f;
#pragma unroll
            for (int ni = 0; ni < 4; ++ni) {
                int col = s0 + ni * 16 + r;
                float sv = (col <= qrow + j) ? s[ni][j] * 0.125f : -3.0e38f;
                s[ni][j] = sv;
                mx = fmaxf(mx, sv);
            }
            tmax[j] = mx;
        }
#pragma unroll
        for (int mk = 1; mk < 16; mk <<= 1)
#pragma unroll
            for (int j = 0; j < 4; ++j) tmax[j] = fmaxf(tmax[j], __shfl_xor(tmax[j], mk));
#pragma unroll
        for (int j = 0; j < 4; ++j) {
            float mnew = fmaxf(mrow[j], tmax[j]);
            fsc[j] = __expf(mrow[j] - mnew);
            mrow[j] = mnew;
            float ss = 0.f;
#pragma unroll
            for (int ni = 0; ni < 4; ++ni) {
                float p = __expf(s[ni][j] - mnew);
                s[ni][j] = p; ss += p;
            }
            tsum[j] = ss;
        }
#pragma unroll
        for (int mk = 1; mk < 16; mk <<= 1)
#pragma unroll
            for (int j = 0; j < 4; ++j) tsum[j] += __shfl_xor(tsum[j], mk);
#pragma unroll
        for (int j = 0; j < 4; ++j) lrow[j] = lrow[j] * fsc[j] + tsum[j];
#pragma unroll
        for (int ni = 0; ni < 4; ++ni)
#pragma unroll
            for (int j = 0; j < 4; ++j) o[ni][j] *= fsc[j];
        // P -> LDS (bf16), per-wave buffer, then PV
#pragma unroll
        for (int ni = 0; ni < 4; ++ni)
#pragma unroll
            for (int j = 0; j < 4; ++j)
                Psm[w][(g << 2) + j][ni * 16 + r] = __float2bfloat16(s[ni][j]);
#pragma unroll
        for (int kk = 0; kk < 2; ++kk) {
            bf16x8 pf = *(const bf16x8*)&Psm[w][r][kk * 32 + ko];
#pragma unroll
            for (int ni = 0; ni < 4; ++ni) {
                bf16x8 vf = *(const bf16x8*)&Vsm[ni * 16 + r][kk * 32 + ko];
                o[ni] = mfma16(pf, vf, o[ni]);
            }
        }
        __syncthreads();
    }

    int b = bh / N_HEAD, h = bh % N_HEAD;
#pragma unroll
    for (int ni = 0; ni < 4; ++ni)
#pragma unroll
        for (int j = 0; j < 4; ++j) {
            int t = q0 + w * 16 + (g << 2) + j;
            int e = h * HEAD + ni * 16 + r;
            att[((size_t)b * T_LEN + t) * D_MODEL + e] = __float2bfloat16(o[ni][j] / lrow[j]);
        }
}

// ---------------- launch ----------------
extern "C" void kernel_launch(void* const* d_in, const int* in_sizes, int n_in,
                              void* d_out, int out_size, void* d_ws, size_t ws_size,
                              hipStream_t stream)
{
    const float* x   = (const float*)d_in[0];
    const float* Wq  = (const float*)d_in[1];
    const float* Wk  = (const float*)d_in[2];
    const float* Wv  = (const float*)d_in[3];
    const float* Wp  = (const float*)d_in[4];
    const float* bp  = (const float*)d_in[5];
    const float* W1  = (const float*)d_in[6];
    const float* b1  = (const float*)d_in[7];
    const float* W2  = (const float*)d_in[8];
    const float* b2  = (const float*)d_in[9];
    const float* g1  = (const float*)d_in[10];
    const float* be1 = (const float*)d_in[11];
    const float* g2  = (const float*)d_in[12];
    const float* be2 = (const float*)d_in[13];
    float* out = (float*)d_out;

    char* ws = (char*)d_ws;
    size_t off = 0;
    auto alloc = [&](size_t bytes) { void* p = ws + off; off += (bytes + 255) & ~(size_t)255; return p; };
    bf16* Wqkv_t = (bf16*)alloc((size_t)1152 * 384 * 2);
    bf16* Wp_t   = (bf16*)alloc((size_t)384 * 384 * 2);
    bf16* W1_t   = (bf16*)alloc((size_t)1536 * 384 * 2);
    bf16* W2_t   = (bf16*)alloc((size_t)384 * 1536 * 2);
    bf16* h      = (bf16*)alloc((size_t)MROWS * 384 * 2);   // also h2 later
    bf16* qb     = (bf16*)alloc((size_t)MROWS * 384 * 2);
    bf16* kb     = (bf16*)alloc((size_t)MROWS * 384 * 2);
    bf16* vTb    = (bf16*)alloc((size_t)MROWS * 384 * 2);
    bf16* attb   = (bf16*)alloc((size_t)MROWS * 384 * 2);
    float* x1    = (float*)alloc((size_t)MROWS * 384 * 4);
    bf16* ff1    = qb;  // alias: q/k/vT/att dead by FFN1 time

    prep_w<<<2304, 256, 0, stream>>>(Wq, Wk, Wv, Wp, W1, W2, Wqkv_t, Wp_t, W1_t, W2_t);
    ln_k<<<MROWS / 4, 256, 0, stream>>>(x, g1, be1, h);
    gemm_k<EPI_QKV><<<(MROWS / 128) * 9, 256, 0, stream>>>(
        h, Wqkv_t, 384, nullptr, nullptr, nullptr, qb, kb, vTb, nullptr);
    attn_k<<<BATCH * N_HEAD * 4, 256, 0, stream>>>(qb, kb, vTb, attb);
    gemm_k<EPI_PROJ><<<(MROWS / 128) * 3, 256, 0, stream>>>(
        attb, Wp_t, 384, bp, x, x1, nullptr, nullptr, nullptr, nullptr);
    ln_k<<<MROWS / 4, 256, 0, stream>>>(x1, g2, be2, h);
    gemm_k<EPI_FFN1><<<(MROWS / 128) * 12, 256, 0, stream>>>(
        h, W1_t, 384, b1, nullptr, nullptr, nullptr, nullptr, nullptr, ff1);
    gemm_k<EPI_FFN2><<<(MROWS / 128) * 3, 256, 0, stream>>>(
        ff1, W2_t, 1536, b2, x1, out, nullptr, nullptr, nullptr, nullptr);
}

// Round 3
// 311.870 us; speedup vs baseline: 1.2169x; 1.1981x over previous
//
#include <hip/hip_runtime.h>
#include <hip/hip_bf16.h>

#define D_MODEL 384
#define N_HEAD  6
#define HEAD    64
#define T_LEN   256
#define BATCH   128
#define MROWS   (BATCH * T_LEN)   // 32768
#define FF      1536

typedef __bf16 bf16x8 __attribute__((ext_vector_type(8)));
typedef float  f32x4  __attribute__((ext_vector_type(4)));
typedef unsigned short us8 __attribute__((ext_vector_type(8)));
using bf16 = __hip_bfloat16;

__device__ inline f32x4 mfma16(bf16x8 a, bf16x8 b, f32x4 c) {
    return __builtin_amdgcn_mfma_f32_16x16x32_bf16(a, b, c, 0, 0, 0);
}

// async global->LDS, 16B per lane; LDS dest = wave-uniform base + lane*16
#define GLOAD_LDS16(g, l) __builtin_amdgcn_global_load_lds( \
    (const __attribute__((address_space(1))) unsigned int*)(g), \
    (__attribute__((address_space(3))) unsigned int*)(l), 16, 0, 0)

// ---------------- weight prep: cast to bf16, transpose to [N][K] ----------------
__global__ __launch_bounds__(256) void prep_w(
    const float* __restrict__ Wq, const float* __restrict__ Wk, const float* __restrict__ Wv,
    const float* __restrict__ Wp, const float* __restrict__ W1, const float* __restrict__ W2,
    bf16* __restrict__ Wqkv_t, bf16* __restrict__ Wp_t,
    bf16* __restrict__ W1_t,   bf16* __restrict__ W2_t)
{
    int i = blockIdx.x * 256 + threadIdx.x;
    if (i < 1152 * 384) {
        int cc = i / 384, d = i - cc * 384;
        const float* src = cc < 384 ? Wq : (cc < 768 ? Wk : Wv);
        int c = cc < 384 ? cc : (cc < 768 ? cc - 384 : cc - 768);
        int h = c >> 6, e = c & 63;
        Wqkv_t[i] = __float2bfloat16(src[(h * 384 + d) * 64 + e]);
    }
    if (i < 384 * 384) {
        int o = i / 384, d = i - o * 384;
        Wp_t[i] = __float2bfloat16(Wp[d * 384 + o]);
    }
    if (i < 1536 * 384) {
        int o = i / 384, d = i - o * 384;          // W1_t[o][d]
        W1_t[i] = __float2bfloat16(W1[d * 1536 + o]);
        int o2 = i / 1536, d2 = i - o2 * 1536;     // W2_t[o2][d2]
        W2_t[i] = __float2bfloat16(W2[d2 * 384 + o2]);
    }
}

// ---------------- layernorm: one wave per row of 384 ----------------
__global__ __launch_bounds__(256) void ln_k(
    const float* __restrict__ xin, const float* __restrict__ gg,
    const float* __restrict__ bb, bf16* __restrict__ outb)
{
    int wid  = blockIdx.x * 4 + (threadIdx.x >> 6);
    int lane = threadIdx.x & 63;
    const float* xr = xin + (size_t)wid * 384;
    float v[6]; float s = 0.f;
#pragma unroll
    for (int i = 0; i < 6; ++i) { v[i] = xr[lane + i * 64]; s += v[i]; }
#pragma unroll
    for (int mk = 1; mk < 64; mk <<= 1) s += __shfl_xor(s, mk);
    float mu = s * (1.f / 384.f);
    float vs = 0.f;
#pragma unroll
    for (int i = 0; i < 6; ++i) { float d = v[i] - mu; vs += d * d; }
#pragma unroll
    for (int mk = 1; mk < 64; mk <<= 1) vs += __shfl_xor(vs, mk);
    float rs = rsqrtf(vs * (1.f / 384.f) + 1e-5f);
    bf16* orow = outb + (size_t)wid * 384;
#pragma unroll
    for (int i = 0; i < 6; ++i) {
        int c = lane + i * 64;
        orow[c] = __float2bfloat16((v[i] - mu) * rs * gg[c] + bb[c]);
    }
}

// ======== 8-wave pipelined GEMM: C[M,N] = A[M,K] @ Bt[N,K]^T, BM=256 BN=192 BK=64
// Counted-vmcnt depth-2 pipeline (T3+T4), XOR-swizzled LDS via pre-swizzled
// global source (T2, rule-21 both-sides), setprio around MFMA (T5),
// chunked XCD swizzle with nt-fastest for A-panel L2 reuse (T1).
enum { EPI_QKV = 0, EPI_PROJ = 1, EPI_FFN1 = 2, EPI_FFN2 = 3 };

template<int EPI, int K, int NTN>
__global__ __launch_bounds__(512) void gemm8(
    const bf16* __restrict__ A, const bf16* __restrict__ Bt,
    const float* __restrict__ bias, const float* __restrict__ resid,
    float* __restrict__ outf,
    bf16* __restrict__ outq, bf16* __restrict__ outk, bf16* __restrict__ outv,
    bf16* __restrict__ outb)
{
    extern __shared__ char smem[];
    bf16* Albase = (bf16*)smem;                  // [2][256][64] elems, buf*16384
    bf16* Blbase = (bf16*)(smem + 65536);        // [2][192][64] elems, buf*12288
    constexpr int NT = K / 64;
    constexpr int nwg = (MROWS / 256) * NTN;     // multiple of 256
    int bid = blockIdx.x;
    int wg = (bid & 7) * (nwg >> 3) + (bid >> 3);   // bijective XCD chunking
    int mt = wg / NTN, nt = wg - mt * NTN;          // nt fastest within chunk
    int m0 = mt * 256, n0 = nt * 192;
    int tid = threadIdx.x, lane = tid & 63, w = tid >> 6;
    int r = lane & 15, g = lane >> 4;
    int lr8 = lane >> 3, l7 = lane & 7;
    int csw = (l7 ^ lr8) << 3;      // pre-swizzled source col offset (elements)
    int wm = (w >> 1) * 64, wn = (w & 1) * 96;
    int sb = g ^ l7;                // read slot base (16B slots)

    const bf16* Ag = A  + (size_t)(m0 + w * 32 + lr8) * K + csw;
    const bf16* Bg = Bt + (size_t)(n0 + w * 24 + lr8) * K + csw;
    const int AL0 = w * 32 * 64;    // wave-uniform LDS element offsets
    const int BL0 = w * 24 * 64;

#define STAGE(tt, bb) do { \
    const bf16* a_ = Ag + (tt) * 64; \
    bf16* al_ = Albase + (bb) * 16384 + AL0; \
    _Pragma("unroll") for (int q_ = 0; q_ < 4; ++q_) \
        GLOAD_LDS16(a_ + (size_t)q_ * 8 * K, al_ + q_ * 8 * 64); \
    const bf16* b_ = Bg + (tt) * 64; \
    bf16* bl_ = Blbase + (bb) * 12288 + BL0; \
    _Pragma("unroll") for (int q_ = 0; q_ < 3; ++q_) \
        GLOAD_LDS16(b_ + (size_t)q_ * 8 * K, bl_ + q_ * 8 * 64); \
} while (0)

    f32x4 acc[4][6];
#pragma unroll
    for (int i = 0; i < 4; ++i)
#pragma unroll
        for (int j = 0; j < 6; ++j) acc[i][j] = (f32x4){0.f, 0.f, 0.f, 0.f};

    STAGE(0, 0);
    STAGE(1, 1);

#define ITER(tt, VM, DOSTAGE) do { \
    int bb_ = (tt) & 1; \
    asm volatile("s_waitcnt vmcnt(" #VM ")" ::: "memory"); \
    __builtin_amdgcn_s_barrier(); \
    __builtin_amdgcn_sched_barrier(0); \
    const bf16* Ar_ = Albase + bb_ * 16384; \
    const bf16* Br_ = Blbase + bb_ * 12288; \
    bf16x8 af[4][2], bfv[6][2]; \
    _Pragma("unroll") for (int mi = 0; mi < 4; ++mi) { \
        int row_ = (wm + mi * 16 + r) * 64; \
        _Pragma("unroll") for (int kk = 0; kk < 2; ++kk) \
            af[mi][kk] = *(const bf16x8*)&Ar_[row_ + ((sb ^ (kk * 4)) << 3)]; \
    } \
    _Pragma("unroll") for (int ni = 0; ni < 6; ++ni) { \
        int row_ = (wn + ni * 16 + r) * 64; \
        _Pragma("unroll") for (int kk = 0; kk < 2; ++kk) \
            bfv[ni][kk] = *(const bf16x8*)&Br_[row_ + ((sb ^ (kk * 4)) << 3)]; \
    } \
    asm volatile("s_waitcnt lgkmcnt(0)" ::: "memory"); \
    __builtin_amdgcn_sched_barrier(0); \
    __builtin_amdgcn_s_barrier(); \
    if (DOSTAGE) STAGE((tt) + 2, bb_); \
    __builtin_amdgcn_s_setprio(1); \
    _Pragma("unroll") for (int kk = 0; kk < 2; ++kk) \
      _Pragma("unroll") for (int mi = 0; mi < 4; ++mi) \
        _Pragma("unroll") for (int ni = 0; ni < 6; ++ni) \
            acc[mi][ni] = mfma16(af[mi][kk], bfv[ni][kk], acc[mi][ni]); \
    __builtin_amdgcn_s_setprio(0); \
} while (0)

#pragma unroll 1
    for (int t = 0; t < NT - 2; ++t) ITER(t, 7, true);
    ITER(NT - 2, 7, false);
    ITER(NT - 1, 0, false);
#undef ITER
#undef STAGE

    // epilogue: C/D layout col = r, row = g*4 + j (m89-verified)
#pragma unroll
    for (int ni = 0; ni < 6; ++ni) {
        int n = n0 + wn + ni * 16 + r;
        float bn = 0.f;
        if constexpr (EPI != EPI_QKV) bn = bias[n];
#pragma unroll
        for (int mi = 0; mi < 4; ++mi) {
#pragma unroll
            for (int j = 0; j < 4; ++j) {
                int m = m0 + wm + mi * 16 + (g << 2) + j;
                float v = acc[mi][ni][j];
                if constexpr (EPI == EPI_QKV) {
                    int b = m >> 8, t = m & 255;
                    if (n < 384) {
                        int h = n >> 6, e = n & 63;
                        outq[((size_t)(b * N_HEAD + h) * T_LEN + t) * HEAD + e] = __float2bfloat16(v);
                    } else if (n < 768) {
                        int c = n - 384; int h = c >> 6, e = c & 63;
                        outk[((size_t)(b * N_HEAD + h) * T_LEN + t) * HEAD + e] = __float2bfloat16(v);
                    } else {
                        int c = n - 768; int h = c >> 6, e = c & 63;
                        outv[((size_t)(b * N_HEAD + h) * HEAD + e) * T_LEN + t] = __float2bfloat16(v);
                    }
                } else if constexpr (EPI == EPI_PROJ || EPI == EPI_FFN2) {
                    outf[(size_t)m * 384 + n] = resid[(size_t)m * 384 + n] + v + bn;
                } else { // FFN1
                    float z = v + bn; z = z > 0.f ? z : 0.f;
                    outb[(size_t)m * FF + n] = __float2bfloat16(z);
                }
            }
        }
    }
}

// ---------------- causal flash attention: block = (b,h,64-row q tile) ----------
__global__ __launch_bounds__(256) void attn_k(
    const bf16* __restrict__ q, const bf16* __restrict__ k,
    const bf16* __restrict__ vT, bf16* __restrict__ att)
{
    __shared__ bf16 Ksm[64][64];
    __shared__ bf16 Vsm[64][64];   // Vsm[e][s_local]
    __shared__ bf16 Psm[4][16][64];
    int bid = blockIdx.x;
    int qt = bid & 3, bh = bid >> 2;
    int q0 = qt * 64;
    int tid = threadIdx.x, lane = tid & 63, w = tid >> 6;
    int r = lane & 15, g = lane >> 4, ko = g << 3;
    int lr = lane >> 3, lc = (lane & 7) << 3;

    const bf16* qp = q + ((size_t)bh * T_LEN + q0 + w * 16) * HEAD;
    bf16x8 qf[2];
    qf[0] = *(const bf16x8*)&qp[r * HEAD + ko];
    qf[1] = *(const bf16x8*)&qp[r * HEAD + ko + 32];

    f32x4 o[4];
#pragma unroll
    for (int i = 0; i < 4; ++i) o[i] = (f32x4){0.f, 0.f, 0.f, 0.f};
    float mrow[4], lrow[4];
#pragma unroll
    for (int j = 0; j < 4; ++j) { mrow[j] = -3.0e38f; lrow[j] = 0.f; }

    for (int st = 0; st <= qt; ++st) {
        int s0 = st * 64;
#pragma unroll
        for (int s = 0; s < 2; ++s) {
            int row0 = w * 16 + s * 8;
            GLOAD_LDS16(k  + ((size_t)bh * T_LEN + s0 + row0 + lr) * HEAD + lc, &Ksm[row0][0]);
            GLOAD_LDS16(vT + ((size_t)bh * HEAD + row0 + lr) * T_LEN + s0 + lc, &Vsm[row0][0]);
        }
        __syncthreads();

        f32x4 s[4];
#pragma unroll
        for (int i = 0; i < 4; ++i) s[i] = (f32x4){0.f, 0.f, 0.f, 0.f};
#pragma unroll
        for (int kk = 0; kk < 2; ++kk) {
#pragma unroll
            for (int ni = 0; ni < 4; ++ni) {
                bf16x8 kf = *(const bf16x8*)&Ksm[ni * 16 + r][kk * 32 + ko];
                s[ni] = mfma16(qf[kk], kf, s[ni]);
            }
        }
        int qrow = q0 + w * 16 + (g << 2);
        float tmax[4], fsc[4], tsum[4];
#pragma unroll
        for (int j = 0; j < 4; ++j) {
            float mx = -3.0e38f;
#pragma unroll
            for (int ni = 0; ni < 4; ++ni) {
                int col = s0 + ni * 16 + r;
                float sv = (col <= qrow + j) ? s[ni][j] * 0.125f : -3.0e38f;
                s[ni][j] = sv;
                mx = fmaxf(mx, sv);
            }
            tmax[j] = mx;
        }
#pragma unroll
        for (int mk = 1; mk < 16; mk <<= 1)
#pragma unroll
            for (int j = 0; j < 4; ++j) tmax[j] = fmaxf(tmax[j], __shfl_xor(tmax[j], mk));
#pragma unroll
        for (int j = 0; j < 4; ++j) {
            float mnew = fmaxf(mrow[j], tmax[j]);
            fsc[j] = __expf(mrow[j] - mnew);
            mrow[j] = mnew;
            float ss = 0.f;
#pragma unroll
            for (int ni = 0; ni < 4; ++ni) {
                float p = __expf(s[ni][j] - mnew);
                s[ni][j] = p; ss += p;
            }
            tsum[j] = ss;
        }
#pragma unroll
        for (int mk = 1; mk < 16; mk <<= 1)
#pragma unroll
            for (int j = 0; j < 4; ++j) tsum[j] += __shfl_xor(tsum[j], mk);
#pragma unroll
        for (int j = 0; j < 4; ++j) lrow[j] = lrow[j] * fsc[j] + tsum[j];
#pragma unroll
        for (int ni = 0; ni < 4; ++ni)
#pragma unroll
            for (int j = 0; j < 4; ++j) o[ni][j] *= fsc[j];
#pragma unroll
        for (int ni = 0; ni < 4; ++ni)
#pragma unroll
            for (int j = 0; j < 4; ++j)
                Psm[w][(g << 2) + j][ni * 16 + r] = __float2bfloat16(s[ni][j]);
#pragma unroll
        for (int kk = 0; kk < 2; ++kk) {
            bf16x8 pf = *(const bf16x8*)&Psm[w][r][kk * 32 + ko];
#pragma unroll
            for (int ni = 0; ni < 4; ++ni) {
                bf16x8 vf = *(const bf16x8*)&Vsm[ni * 16 + r][kk * 32 + ko];
                o[ni] = mfma16(pf, vf, o[ni]);
            }
        }
        __syncthreads();
    }

    int b = bh / N_HEAD, h = bh % N_HEAD;
#pragma unroll
    for (int ni = 0; ni < 4; ++ni)
#pragma unroll
        for (int j = 0; j < 4; ++j) {
            int t = q0 + w * 16 + (g << 2) + j;
            int e = h * HEAD + ni * 16 + r;
            att[((size_t)b * T_LEN + t) * D_MODEL + e] = __float2bfloat16(o[ni][j] / lrow[j]);
        }
}

// ---------------- launch ----------------
#define GEMM_SMEM 114688

extern "C" void kernel_launch(void* const* d_in, const int* in_sizes, int n_in,
                              void* d_out, int out_size, void* d_ws, size_t ws_size,
                              hipStream_t stream)
{
    const float* x   = (const float*)d_in[0];
    const float* Wq  = (const float*)d_in[1];
    const float* Wk  = (const float*)d_in[2];
    const float* Wv  = (const float*)d_in[3];
    const float* Wp  = (const float*)d_in[4];
    const float* bp  = (const float*)d_in[5];
    const float* W1  = (const float*)d_in[6];
    const float* b1  = (const float*)d_in[7];
    const float* W2  = (const float*)d_in[8];
    const float* b2  = (const float*)d_in[9];
    const float* g1  = (const float*)d_in[10];
    const float* be1 = (const float*)d_in[11];
    const float* g2  = (const float*)d_in[12];
    const float* be2 = (const float*)d_in[13];
    float* out = (float*)d_out;

    char* ws = (char*)d_ws;
    size_t off = 0;
    auto alloc = [&](size_t bytes) { void* p = ws + off; off += (bytes + 255) & ~(size_t)255; return p; };
    bf16* Wqkv_t = (bf16*)alloc((size_t)1152 * 384 * 2);
    bf16* Wp_t   = (bf16*)alloc((size_t)384 * 384 * 2);
    bf16* W1_t   = (bf16*)alloc((size_t)1536 * 384 * 2);
    bf16* W2_t   = (bf16*)alloc((size_t)384 * 1536 * 2);
    bf16* h      = (bf16*)alloc((size_t)MROWS * 384 * 2);   // also h2 later
    bf16* qb     = (bf16*)alloc((size_t)MROWS * 384 * 2);
    bf16* kb     = (bf16*)alloc((size_t)MROWS * 384 * 2);
    bf16* vTb    = (bf16*)alloc((size_t)MROWS * 384 * 2);
    bf16* attb   = (bf16*)alloc((size_t)MROWS * 384 * 2);
    float* x1    = (float*)alloc((size_t)MROWS * 384 * 4);
    bf16* ff1    = qb;  // alias: q/k/vT/att dead by FFN1 time

    hipFuncSetAttribute(reinterpret_cast<const void*>(&gemm8<EPI_QKV, 384, 6>),
                        hipFuncAttributeMaxDynamicSharedMemorySize, GEMM_SMEM);
    hipFuncSetAttribute(reinterpret_cast<const void*>(&gemm8<EPI_PROJ, 384, 2>),
                        hipFuncAttributeMaxDynamicSharedMemorySize, GEMM_SMEM);
    hipFuncSetAttribute(reinterpret_cast<const void*>(&gemm8<EPI_FFN1, 384, 8>),
                        hipFuncAttributeMaxDynamicSharedMemorySize, GEMM_SMEM);
    hipFuncSetAttribute(reinterpret_cast<const void*>(&gemm8<EPI_FFN2, 1536, 2>),
                        hipFuncAttributeMaxDynamicSharedMemorySize, GEMM_SMEM);

    prep_w<<<2304, 256, 0, stream>>>(Wq, Wk, Wv, Wp, W1, W2, Wqkv_t, Wp_t, W1_t, W2_t);
    ln_k<<<MROWS / 4, 256, 0, stream>>>(x, g1, be1, h);
    gemm8<EPI_QKV, 384, 6><<<768, 512, GEMM_SMEM, stream>>>(
        h, Wqkv_t, nullptr, nullptr, nullptr, qb, kb, vTb, nullptr);
    attn_k<<<BATCH * N_HEAD * 4, 256, 0, stream>>>(qb, kb, vTb, attb);
    gemm8<EPI_PROJ, 384, 2><<<256, 512, GEMM_SMEM, stream>>>(
        attb, Wp_t, bp, x, x1, nullptr, nullptr, nullptr, nullptr);
    ln_k<<<MROWS / 4, 256, 0, stream>>>(x1, g2, be2, h);
    gemm8<EPI_FFN1, 384, 8><<<1024, 512, GEMM_SMEM, stream>>>(
        h, W1_t, b1, nullptr, nullptr, nullptr, nullptr, nullptr, ff1);
    gemm8<EPI_FFN2, 1536, 2><<<256, 512, GEMM_SMEM, stream>>>(
        ff1, W2_t, b2, x1, out, nullptr, nullptr, nullptr, nullptr);
}

// Round 4
// 294.750 us; speedup vs baseline: 1.2876x; 1.0581x over previous
//
#include <hip/hip_runtime.h>
#include <hip/hip_bf16.h>

#define D_MODEL 384
#define N_HEAD  6
#define HEAD    64
#define T_LEN   256
#define BATCH   128
#define MROWS   (BATCH * T_LEN)   // 32768
#define FF      1536

typedef __bf16 bf16x8 __attribute__((ext_vector_type(8)));
typedef float  f32x4  __attribute__((ext_vector_type(4)));
typedef unsigned short us8 __attribute__((ext_vector_type(8)));
using bf16 = __hip_bfloat16;

__device__ inline f32x4 mfma16(bf16x8 a, bf16x8 b, f32x4 c) {
    return __builtin_amdgcn_mfma_f32_16x16x32_bf16(a, b, c, 0, 0, 0);
}

// async global->LDS, 16B per lane; LDS dest = wave-uniform base + lane*16
#define GLOAD_LDS16(g, l) __builtin_amdgcn_global_load_lds( \
    (const __attribute__((address_space(1))) unsigned int*)(g), \
    (__attribute__((address_space(3))) unsigned int*)(l), 16, 0, 0)

// ---------------- weight prep: cast to bf16, transpose to [N][K] ----------------
__global__ __launch_bounds__(256) void prep_w(
    const float* __restrict__ Wq, const float* __restrict__ Wk, const float* __restrict__ Wv,
    const float* __restrict__ Wp, const float* __restrict__ W1, const float* __restrict__ W2,
    bf16* __restrict__ Wqkv_t, bf16* __restrict__ Wp_t,
    bf16* __restrict__ W1_t,   bf16* __restrict__ W2_t)
{
    int i = blockIdx.x * 256 + threadIdx.x;
    if (i < 1152 * 384) {
        int cc = i / 384, d = i - cc * 384;
        const float* src = cc < 384 ? Wq : (cc < 768 ? Wk : Wv);
        int c = cc < 384 ? cc : (cc < 768 ? cc - 384 : cc - 768);
        int h = c >> 6, e = c & 63;
        Wqkv_t[i] = __float2bfloat16(src[(h * 384 + d) * 64 + e]);
    }
    if (i < 384 * 384) {
        int o = i / 384, d = i - o * 384;
        Wp_t[i] = __float2bfloat16(Wp[d * 384 + o]);
    }
    if (i < 1536 * 384) {
        int o = i / 384, d = i - o * 384;          // W1_t[o][d]
        W1_t[i] = __float2bfloat16(W1[d * 1536 + o]);
        int o2 = i / 1536, d2 = i - o2 * 1536;     // W2_t[o2][d2]
        W2_t[i] = __float2bfloat16(W2[d2 * 384 + o2]);
    }
}

// ---------------- layernorm: one wave per row of 384 ----------------
__global__ __launch_bounds__(256) void ln_k(
    const float* __restrict__ xin, const float* __restrict__ gg,
    const float* __restrict__ bb, bf16* __restrict__ outb)
{
    int wid  = blockIdx.x * 4 + (threadIdx.x >> 6);
    int lane = threadIdx.x & 63;
    const float* xr = xin + (size_t)wid * 384;
    float v[6]; float s = 0.f;
#pragma unroll
    for (int i = 0; i < 6; ++i) { v[i] = xr[lane + i * 64]; s += v[i]; }
#pragma unroll
    for (int mk = 1; mk < 64; mk <<= 1) s += __shfl_xor(s, mk);
    float mu = s * (1.f / 384.f);
    float vs = 0.f;
#pragma unroll
    for (int i = 0; i < 6; ++i) { float d = v[i] - mu; vs += d * d; }
#pragma unroll
    for (int mk = 1; mk < 64; mk <<= 1) vs += __shfl_xor(vs, mk);
    float rs = rsqrtf(vs * (1.f / 384.f) + 1e-5f);
    bf16* orow = outb + (size_t)wid * 384;
#pragma unroll
    for (int i = 0; i < 6; ++i) {
        int c = lane + i * 64;
        orow[c] = __float2bfloat16((v[i] - mu) * rs * gg[c] + bb[c]);
    }
}

// ---------------- v[b,h,t,e] -> vT[b,h,e,t] coalesced LDS transpose -----------
__global__ __launch_bounds__(256) void tr_v(
    const bf16* __restrict__ v, bf16* __restrict__ vT)
{
    __shared__ bf16 L[256][68];   // +4 pad
    int bh = blockIdx.x;
    int tid = threadIdx.x;
    const bf16* src = v + (size_t)bh * T_LEN * HEAD + (size_t)tid * HEAD;
#pragma unroll
    for (int c = 0; c < 8; ++c)
        *(us8*)&L[tid][c * 8] = *(const us8*)&src[c * 8];
    __syncthreads();
    bf16* dst = vT + (size_t)bh * HEAD * T_LEN;
#pragma unroll
    for (int i = 0; i < 8; ++i) {
        int idx = tid + i * 256;            // 0..2047
        int e = idx >> 5, tc = (idx & 31) * 8;
        bf16x8 pk;
#pragma unroll
        for (int j = 0; j < 8; ++j) pk[j] = *(__bf16*)&L[tc + j][e];
        *(bf16x8*)&dst[(size_t)e * T_LEN + tc] = pk;
    }
}

// ======== 8-wave pipelined GEMM: C[M,N] = A[M,K] @ Bt[N,K]^T, BM=256 BN=192 BK=64
enum { EPI_QKV = 0, EPI_PROJ = 1, EPI_FFN1 = 2, EPI_FFN2 = 3 };

template<int EPI, int K, int NTN>
__global__ __launch_bounds__(512) void gemm8(
    const bf16* __restrict__ A, const bf16* __restrict__ Bt,
    const float* __restrict__ bias, const float* __restrict__ resid,
    float* __restrict__ outf,
    bf16* __restrict__ outq, bf16* __restrict__ outk, bf16* __restrict__ outv,
    bf16* __restrict__ outb)
{
    extern __shared__ char smem[];
    bf16* Albase = (bf16*)smem;                  // [2][256][64] elems, buf*16384
    bf16* Blbase = (bf16*)(smem + 65536);        // [2][192][64] elems, buf*12288
    constexpr int NT = K / 64;
    constexpr int nwg = (MROWS / 256) * NTN;     // multiple of 256
    int bid = blockIdx.x;
    int wg = (bid & 7) * (nwg >> 3) + (bid >> 3);   // bijective XCD chunking
    int mt = wg / NTN, nt = wg - mt * NTN;          // nt fastest within chunk
    int m0 = mt * 256, n0 = nt * 192;
    int tid = threadIdx.x, lane = tid & 63, w = tid >> 6;
    int r = lane & 15, g = lane >> 4;
    int lr8 = lane >> 3, l7 = lane & 7;
    int csw = (l7 ^ lr8) << 3;      // pre-swizzled source col offset (elements)
    int wm = (w >> 1) * 64, wn = (w & 1) * 96;
    int sb = g ^ l7;                // read slot base (16B slots)

    const bf16* Ag = A  + (size_t)(m0 + w * 32 + lr8) * K + csw;
    const bf16* Bg = Bt + (size_t)(n0 + w * 24 + lr8) * K + csw;
    const int AL0 = w * 32 * 64;    // wave-uniform LDS element offsets
    const int BL0 = w * 24 * 64;

#define STAGE(tt, bb) do { \
    const bf16* a_ = Ag + (tt) * 64; \
    bf16* al_ = Albase + (bb) * 16384 + AL0; \
    _Pragma("unroll") for (int q_ = 0; q_ < 4; ++q_) \
        GLOAD_LDS16(a_ + (size_t)q_ * 8 * K, al_ + q_ * 8 * 64); \
    const bf16* b_ = Bg + (tt) * 64; \
    bf16* bl_ = Blbase + (bb) * 12288 + BL0; \
    _Pragma("unroll") for (int q_ = 0; q_ < 3; ++q_) \
        GLOAD_LDS16(b_ + (size_t)q_ * 8 * K, bl_ + q_ * 8 * 64); \
} while (0)

    f32x4 acc[4][6];
#pragma unroll
    for (int i = 0; i < 4; ++i)
#pragma unroll
        for (int j = 0; j < 6; ++j) acc[i][j] = (f32x4){0.f, 0.f, 0.f, 0.f};

    STAGE(0, 0);
    STAGE(1, 1);

#define ITER(tt, VM, DOSTAGE) do { \
    int bb_ = (tt) & 1; \
    asm volatile("s_waitcnt vmcnt(" #VM ")" ::: "memory"); \
    __builtin_amdgcn_s_barrier(); \
    __builtin_amdgcn_sched_barrier(0); \
    const bf16* Ar_ = Albase + bb_ * 16384; \
    const bf16* Br_ = Blbase + bb_ * 12288; \
    bf16x8 af[4][2], bfv[6][2]; \
    _Pragma("unroll") for (int mi = 0; mi < 4; ++mi) { \
        int row_ = (wm + mi * 16 + r) * 64; \
        _Pragma("unroll") for (int kk = 0; kk < 2; ++kk) \
            af[mi][kk] = *(const bf16x8*)&Ar_[row_ + ((sb ^ (kk * 4)) << 3)]; \
    } \
    _Pragma("unroll") for (int ni = 0; ni < 6; ++ni) { \
        int row_ = (wn + ni * 16 + r) * 64; \
        _Pragma("unroll") for (int kk = 0; kk < 2; ++kk) \
            bfv[ni][kk] = *(const bf16x8*)&Br_[row_ + ((sb ^ (kk * 4)) << 3)]; \
    } \
    asm volatile("s_waitcnt lgkmcnt(0)" ::: "memory"); \
    __builtin_amdgcn_sched_barrier(0); \
    __builtin_amdgcn_s_barrier(); \
    if (DOSTAGE) STAGE((tt) + 2, bb_); \
    __builtin_amdgcn_s_setprio(1); \
    _Pragma("unroll") for (int kk = 0; kk < 2; ++kk) \
      _Pragma("unroll") for (int mi = 0; mi < 4; ++mi) \
        _Pragma("unroll") for (int ni = 0; ni < 6; ++ni) \
            acc[mi][ni] = mfma16(af[mi][kk], bfv[ni][kk], acc[mi][ni]); \
    __builtin_amdgcn_s_setprio(0); \
} while (0)

#pragma unroll 1
    for (int t = 0; t < NT - 2; ++t) ITER(t, 7, true);
    ITER(NT - 2, 7, false);
    ITER(NT - 1, 0, false);
#undef ITER
#undef STAGE

    // epilogue: C/D layout col = r, row = g*4 + j (m89-verified)
#pragma unroll
    for (int ni = 0; ni < 6; ++ni) {
        int n = n0 + wn + ni * 16 + r;
        float bn = 0.f;
        if constexpr (EPI != EPI_QKV) bn = bias[n];
#pragma unroll
        for (int mi = 0; mi < 4; ++mi) {
#pragma unroll
            for (int j = 0; j < 4; ++j) {
                int m = m0 + wm + mi * 16 + (g << 2) + j;
                float v = acc[mi][ni][j];
                if constexpr (EPI == EPI_QKV) {
                    int b = m >> 8, t = m & 255;
                    // all three outputs coalesced [b,h,t,e]; v transposed later
                    bf16* dst; int c;
                    if (n < 384)      { dst = outq; c = n; }
                    else if (n < 768) { dst = outk; c = n - 384; }
                    else              { dst = outv; c = n - 768; }
                    int h = c >> 6, e = c & 63;
                    dst[((size_t)(b * N_HEAD + h) * T_LEN + t) * HEAD + e] = __float2bfloat16(v);
                } else if constexpr (EPI == EPI_PROJ || EPI == EPI_FFN2) {
                    outf[(size_t)m * 384 + n] = resid[(size_t)m * 384 + n] + v + bn;
                } else { // FFN1
                    float z = v + bn; z = z > 0.f ? z : 0.f;
                    outb[(size_t)m * FF + n] = __float2bfloat16(z);
                }
            }
        }
    }
}

// ---------------- causal flash attention: block = (b,h,64-row q tile) ----------
__global__ __launch_bounds__(256) void attn_k(
    const bf16* __restrict__ q, const bf16* __restrict__ k,
    const bf16* __restrict__ vT, bf16* __restrict__ att)
{
    __shared__ bf16 Ksm[64][64];
    __shared__ bf16 Vsm[64][64];   // Vsm[e][s_local]
    __shared__ bf16 Psm[4][16][64];
    int bid = blockIdx.x;
    int qt = bid & 3, bh = bid >> 2;
    int q0 = qt * 64;
    int tid = threadIdx.x, lane = tid & 63, w = tid >> 6;
    int r = lane & 15, g = lane >> 4, ko = g << 3;
    int lr = lane >> 3, lc = (lane & 7) << 3;

    const bf16* qp = q + ((size_t)bh * T_LEN + q0 + w * 16) * HEAD;
    bf16x8 qf[2];
    qf[0] = *(const bf16x8*)&qp[r * HEAD + ko];
    qf[1] = *(const bf16x8*)&qp[r * HEAD + ko + 32];

    f32x4 o[4];
#pragma unroll
    for (int i = 0; i < 4; ++i) o[i] = (f32x4){0.f, 0.f, 0.f, 0.f};
    float mrow[4], lrow[4];
#pragma unroll
    for (int j = 0; j < 4; ++j) { mrow[j] = -3.0e38f; lrow[j] = 0.f; }

    for (int st = 0; st <= qt; ++st) {
        int s0 = st * 64;
#pragma unroll
        for (int s = 0; s < 2; ++s) {
            int row0 = w * 16 + s * 8;
            GLOAD_LDS16(k  + ((size_t)bh * T_LEN + s0 + row0 + lr) * HEAD + lc, &Ksm[row0][0]);
            GLOAD_LDS16(vT + ((size_t)bh * HEAD + row0 + lr) * T_LEN + s0 + lc, &Vsm[row0][0]);
        }
        __syncthreads();

        f32x4 s[4];
#pragma unroll
        for (int i = 0; i < 4; ++i) s[i] = (f32x4){0.f, 0.f, 0.f, 0.f};
#pragma unroll
        for (int kk = 0; kk < 2; ++kk) {
#pragma unroll
            for (int ni = 0; ni < 4; ++ni) {
                bf16x8 kf = *(const bf16x8*)&Ksm[ni * 16 + r][kk * 32 + ko];
                s[ni] = mfma16(qf[kk], kf, s[ni]);
            }
        }
        int qrow = q0 + w * 16 + (g << 2);
        float tmax[4], fsc[4], tsum[4];
#pragma unroll
        for (int j = 0; j < 4; ++j) {
            float mx = -3.0e38f;
#pragma unroll
            for (int ni = 0; ni < 4; ++ni) {
                int col = s0 + ni * 16 + r;
                float sv = (col <= qrow + j) ? s[ni][j] * 0.125f : -3.0e38f;
                s[ni][j] = sv;
                mx = fmaxf(mx, sv);
            }
            tmax[j] = mx;
        }
#pragma unroll
        for (int mk = 1; mk < 16; mk <<= 1)
#pragma unroll
            for (int j = 0; j < 4; ++j) tmax[j] = fmaxf(tmax[j], __shfl_xor(tmax[j], mk));
#pragma unroll
        for (int j = 0; j < 4; ++j) {
            float mnew = fmaxf(mrow[j], tmax[j]);
            fsc[j] = __expf(mrow[j] - mnew);
            mrow[j] = mnew;
            float ss = 0.f;
#pragma unroll
            for (int ni = 0; ni < 4; ++ni) {
                float p = __expf(s[ni][j] - mnew);
                s[ni][j] = p; ss += p;
            }
            tsum[j] = ss;
        }
#pragma unroll
        for (int mk = 1; mk < 16; mk <<= 1)
#pragma unroll
            for (int j = 0; j < 4; ++j) tsum[j] += __shfl_xor(tsum[j], mk);
#pragma unroll
        for (int j = 0; j < 4; ++j) lrow[j] = lrow[j] * fsc[j] + tsum[j];
#pragma unroll
        for (int ni = 0; ni < 4; ++ni)
#pragma unroll
            for (int j = 0; j < 4; ++j) o[ni][j] *= fsc[j];
#pragma unroll
        for (int ni = 0; ni < 4; ++ni)
#pragma unroll
            for (int j = 0; j < 4; ++j)
                Psm[w][(g << 2) + j][ni * 16 + r] = __float2bfloat16(s[ni][j]);
#pragma unroll
        for (int kk = 0; kk < 2; ++kk) {
            bf16x8 pf = *(const bf16x8*)&Psm[w][r][kk * 32 + ko];
#pragma unroll
            for (int ni = 0; ni < 4; ++ni) {
                bf16x8 vf = *(const bf16x8*)&Vsm[ni * 16 + r][kk * 32 + ko];
                o[ni] = mfma16(pf, vf, o[ni]);
            }
        }
        __syncthreads();
    }

    int b = bh / N_HEAD, h = bh % N_HEAD;
#pragma unroll
    for (int ni = 0; ni < 4; ++ni)
#pragma unroll
        for (int j = 0; j < 4; ++j) {
            int t = q0 + w * 16 + (g << 2) + j;
            int e = h * HEAD + ni * 16 + r;
            att[((size_t)b * T_LEN + t) * D_MODEL + e] = __float2bfloat16(o[ni][j] / lrow[j]);
        }
}

// ---------------- launch ----------------
#define GEMM_SMEM 114688

extern "C" void kernel_launch(void* const* d_in, const int* in_sizes, int n_in,
                              void* d_out, int out_size, void* d_ws, size_t ws_size,
                              hipStream_t stream)
{
    const float* x   = (const float*)d_in[0];
    const float* Wq  = (const float*)d_in[1];
    const float* Wk  = (const float*)d_in[2];
    const float* Wv  = (const float*)d_in[3];
    const float* Wp  = (const float*)d_in[4];
    const float* bp  = (const float*)d_in[5];
    const float* W1  = (const float*)d_in[6];
    const float* b1  = (const float*)d_in[7];
    const float* W2  = (const float*)d_in[8];
    const float* b2  = (const float*)d_in[9];
    const float* g1  = (const float*)d_in[10];
    const float* be1 = (const float*)d_in[11];
    const float* g2  = (const float*)d_in[12];
    const float* be2 = (const float*)d_in[13];
    float* out = (float*)d_out;

    char* ws = (char*)d_ws;
    size_t off = 0;
    auto alloc = [&](size_t bytes) { void* p = ws + off; off += (bytes + 255) & ~(size_t)255; return p; };
    bf16* Wqkv_t = (bf16*)alloc((size_t)1152 * 384 * 2);
    bf16* Wp_t   = (bf16*)alloc((size_t)384 * 384 * 2);
    bf16* W1_t   = (bf16*)alloc((size_t)1536 * 384 * 2);
    bf16* W2_t   = (bf16*)alloc((size_t)384 * 1536 * 2);
    bf16* h      = (bf16*)alloc((size_t)MROWS * 384 * 2);   // also h2 later
    bf16* qb     = (bf16*)alloc((size_t)MROWS * 384 * 2);
    bf16* kb     = (bf16*)alloc((size_t)MROWS * 384 * 2);
    bf16* vTb    = (bf16*)alloc((size_t)MROWS * 384 * 2);
    bf16* attb   = (bf16*)alloc((size_t)MROWS * 384 * 2);
    float* x1    = (float*)alloc((size_t)MROWS * 384 * 4);
    bf16* ff1    = qb;            // alias: q/k/vT/att dead by FFN1 time
    bf16* vb     = (bf16*)x1;     // alias: raw v dead before PROJ writes x1

    hipFuncSetAttribute(reinterpret_cast<const void*>(&gemm8<EPI_QKV, 384, 6>),
                        hipFuncAttributeMaxDynamicSharedMemorySize, GEMM_SMEM);
    hipFuncSetAttribute(reinterpret_cast<const void*>(&gemm8<EPI_PROJ, 384, 2>),
                        hipFuncAttributeMaxDynamicSharedMemorySize, GEMM_SMEM);
    hipFuncSetAttribute(reinterpret_cast<const void*>(&gemm8<EPI_FFN1, 384, 8>),
                        hipFuncAttributeMaxDynamicSharedMemorySize, GEMM_SMEM);
    hipFuncSetAttribute(reinterpret_cast<const void*>(&gemm8<EPI_FFN2, 1536, 2>),
                        hipFuncAttributeMaxDynamicSharedMemorySize, GEMM_SMEM);

    prep_w<<<2304, 256, 0, stream>>>(Wq, Wk, Wv, Wp, W1, W2, Wqkv_t, Wp_t, W1_t, W2_t);
    ln_k<<<MROWS / 4, 256, 0, stream>>>(x, g1, be1, h);
    gemm8<EPI_QKV, 384, 6><<<768, 512, GEMM_SMEM, stream>>>(
        h, Wqkv_t, nullptr, nullptr, nullptr, qb, kb, vb, nullptr);
    tr_v<<<BATCH * N_HEAD, 256, 0, stream>>>(vb, vTb);
    attn_k<<<BATCH * N_HEAD * 4, 256, 0, stream>>>(qb, kb, vTb, attb);
    gemm8<EPI_PROJ, 384, 2><<<256, 512, GEMM_SMEM, stream>>>(
        attb, Wp_t, bp, x, x1, nullptr, nullptr, nullptr, nullptr);
    ln_k<<<MROWS / 4, 256, 0, stream>>>(x1, g2, be2, h);
    gemm8<EPI_FFN1, 384, 8><<<1024, 512, GEMM_SMEM, stream>>>(
        h, W1_t, b1, nullptr, nullptr, nullptr, nullptr, nullptr, ff1);
    gemm8<EPI_FFN2, 1536, 2><<<256, 512, GEMM_SMEM, stream>>>(
        ff1, W2_t, b2, x1, out, nullptr, nullptr, nullptr, nullptr);
}